// Round 1
// baseline (184.559 us; speedup 1.0000x reference)
//
#include <hip/hip_runtime.h>

typedef unsigned short u16;
typedef __attribute__((ext_vector_type(8))) short bf16x8;
typedef __attribute__((ext_vector_type(4))) float f32x4;

#define B_  8
#define S_  2048
#define IN_ 256
#define D_  1024
#define OUT_ 256
#define M_  (B_*S_)   // 16384

// ---- workspace layout (bytes) ----
#define OFF_WIT   0UL                      // 1024*256*2      = 524288   bf16 Wi^T
#define OFF_H     524288UL                 // 16384*1024*2    = 33554432 bf16 h
#define OFF_QPART 34078720UL               // 8*8*1024*4      = 262144
#define OFF_Q     34340864UL               // 8*1024*4
#define OFF_U     34373632UL               // 8*1024*4
#define OFF_SC    34406400UL               // 8*2048*4
#define OFF_W     34471936UL               // 8*2048*4
#define OFF_HPART 34537472UL               // 16*8*1024*4     = 524288
#define OFF_HBAR  35061760UL               // 8*1024*4
#define OFF_APART 35094528UL               // 8*8*1024*4
#define OFF_ABAR  35356672UL               // 8*1024*4
#define OFF_OPART 35389440UL               // 4*8*256*4

static __device__ __forceinline__ float bf2f(u16 u) {
    union { unsigned i; float f; } x; x.i = ((unsigned)u) << 16; return x.f;
}
static __device__ __forceinline__ u16 f2bf(float f) {
    union { float f; unsigned i; } x; x.f = f;
    unsigned r = x.i + 0x7FFFu + ((x.i >> 16) & 1u);
    return (u16)(r >> 16);
}
// int holding two packed bf16 (low = elem0, high = elem1) -> two floats
static __device__ __forceinline__ float2 bf2x2(int p) {
    union { unsigned i; float f; } a, b;
    a.i = ((unsigned)p) << 16;
    b.i = ((unsigned)p) & 0xFFFF0000u;
    float2 r; r.x = a.f; r.y = b.f; return r;
}

// ---------- K0: Wi (256x1024 f32) -> WiT (1024x256 bf16) ----------
__global__ __launch_bounds__(256) void k_wit(const float* __restrict__ Wi, u16* __restrict__ WiT) {
    __shared__ float t[64][65];
    const int tid = threadIdx.x;
    const int n0 = blockIdx.x * 64;   // over N=1024
    const int k0 = blockIdx.y * 64;   // over K=256
    const int c = tid & 63, rr = tid >> 6;
#pragma unroll
    for (int p = 0; p < 16; ++p) {
        int r = p * 4 + rr;
        t[r][c] = Wi[(k0 + r) * 1024 + n0 + c];
    }
    __syncthreads();
#pragma unroll
    for (int p = 0; p < 16; ++p) {
        int n = p * 4 + rr;
        WiT[(n0 + n) * 256 + k0 + c] = f2bf(t[c][n]);
    }
}

// ---------- K1: h = x @ Wi + bi  (MFMA bf16, 128x128 tile) ----------
__global__ __launch_bounds__(256) void k_hgemm(const float* __restrict__ x,
                                               const u16* __restrict__ WiT,
                                               const float* __restrict__ bi,
                                               u16* __restrict__ h) {
    __shared__ u16 lA[128 * 128];
    __shared__ u16 lB[128 * 128];
    const int tid = threadIdx.x;
    const int l = tid & 63, w = tid >> 6;
    const int wm = w >> 1, wn = w & 1;
    const int m0 = blockIdx.y * 128, n0 = blockIdx.x * 128;
    const int q = l >> 4, r = l & 15;

    f32x4 acc[4][4];
#pragma unroll
    for (int mt = 0; mt < 4; ++mt)
#pragma unroll
        for (int nt = 0; nt < 4; ++nt)
            acc[mt][nt] = (f32x4){0.f, 0.f, 0.f, 0.f};

    for (int kh = 0; kh < 2; ++kh) {
        if (kh) __syncthreads();
        // stage A: x tile 128 rows x 128 k (fp32 -> bf16), swizzled
#pragma unroll
        for (int p = 0; p < 8; ++p) {
            int id = p * 256 + tid;
            int row = id >> 4, cb = id & 15;
            const float4* src = reinterpret_cast<const float4*>(&x[(m0 + row) * IN_ + kh * 128 + cb * 8]);
            float4 v0 = src[0], v1 = src[1];
            u16 tmp[8];
            tmp[0] = f2bf(v0.x); tmp[1] = f2bf(v0.y); tmp[2] = f2bf(v0.z); tmp[3] = f2bf(v0.w);
            tmp[4] = f2bf(v1.x); tmp[5] = f2bf(v1.y); tmp[6] = f2bf(v1.z); tmp[7] = f2bf(v1.w);
            int4 pk;
            pk.x = (int)tmp[0] | ((int)tmp[1] << 16);
            pk.y = (int)tmp[2] | ((int)tmp[3] << 16);
            pk.z = (int)tmp[4] | ((int)tmp[5] << 16);
            pk.w = (int)tmp[6] | ((int)tmp[7] << 16);
            *reinterpret_cast<int4*>(&lA[row * 128 + ((cb ^ (row & 7)) << 3)]) = pk;
        }
        // stage B: WiT tile 128 rows x 128 k (bf16 copy), swizzled
#pragma unroll
        for (int p = 0; p < 8; ++p) {
            int id = p * 256 + tid;
            int row = id >> 4, cb = id & 15;
            int4 v = *reinterpret_cast<const int4*>(&WiT[(n0 + row) * IN_ + kh * 128 + cb * 8]);
            *reinterpret_cast<int4*>(&lB[row * 128 + ((cb ^ (row & 7)) << 3)]) = v;
        }
        __syncthreads();
#pragma unroll
        for (int kk = 0; kk < 4; ++kk) {
            int cb = kk * 4 + q;
            bf16x8 af[4], bfr[4];
#pragma unroll
            for (int mt = 0; mt < 4; ++mt) {
                int row = wm * 64 + mt * 16 + r;
                af[mt] = *reinterpret_cast<const bf16x8*>(&lA[row * 128 + ((cb ^ (row & 7)) << 3)]);
            }
#pragma unroll
            for (int nt = 0; nt < 4; ++nt) {
                int row = wn * 64 + nt * 16 + r;
                bfr[nt] = *reinterpret_cast<const bf16x8*>(&lB[row * 128 + ((cb ^ (row & 7)) << 3)]);
            }
#pragma unroll
            for (int mt = 0; mt < 4; ++mt)
#pragma unroll
                for (int nt = 0; nt < 4; ++nt)
                    acc[mt][nt] = __builtin_amdgcn_mfma_f32_16x16x32_bf16(af[mt], bfr[nt], acc[mt][nt], 0, 0, 0);
        }
    }
    // epilogue: h = acc + bi, store bf16.  C/D map: col=lane&15, row=(lane>>4)*4+j
#pragma unroll
    for (int nt = 0; nt < 4; ++nt) {
        int col = n0 + wn * 64 + nt * 16 + r;
        float bival = bi[col];
#pragma unroll
        for (int mt = 0; mt < 4; ++mt) {
#pragma unroll
            for (int j = 0; j < 4; ++j) {
                int row = m0 + wm * 64 + mt * 16 + q * 4 + j;
                h[(size_t)row * D_ + col] = f2bf(acc[mt][nt][j] + bival);
            }
        }
    }
}

// ---------- Q partial: Q[b][e] partial over d-chunk ----------
__global__ __launch_bounds__(256) void k_qpart(const u16* __restrict__ h, const float* __restrict__ Wq,
                                               float* __restrict__ part) {
    const int ec = blockIdx.x, dc = blockIdx.y, b = blockIdx.z, tid = threadIdx.x;
    __shared__ float hl[128];
    if (tid < 128) hl[tid] = bf2f(h[((size_t)(b * S_ + S_ - 1)) * D_ + dc * 128 + tid]);
    __syncthreads();
    const int e = ec * 256 + tid;
    float acc = 0.f;
#pragma unroll 4
    for (int i = 0; i < 128; ++i)
        acc += hl[i] * Wq[(size_t)(dc * 128 + i) * D_ + e];
    part[(dc * 8 + b) * D_ + e] = acc;
}

__global__ __launch_bounds__(256) void k_qreduce(const float* __restrict__ part, const float* __restrict__ bq,
                                                 float* __restrict__ Q) {
    const int e = blockIdx.x * 256 + threadIdx.x, b = blockIdx.y;
    float s = bq[e];
#pragma unroll
    for (int dc = 0; dc < 8; ++dc) s += part[(dc * 8 + b) * D_ + e];
    Q[b * D_ + e] = s;
}

// ---------- u = Wk @ Q ----------
__global__ __launch_bounds__(256) void k_u(const float* __restrict__ Wk, const float* __restrict__ Q,
                                           float* __restrict__ u) {
    const int b = blockIdx.y;
    const int w = threadIdx.x >> 6, l = threadIdx.x & 63;
    const int dbase = blockIdx.x * 16 + w * 4;
    const float* qb = &Q[b * D_];
    float4 qv[4];
#pragma unroll
    for (int p = 0; p < 4; ++p) qv[p] = *reinterpret_cast<const float4*>(&qb[p * 256 + l * 4]);
#pragma unroll
    for (int i = 0; i < 4; ++i) {
        const int d = dbase + i;
        const float* wr = &Wk[(size_t)d * D_];
        float acc = 0.f;
#pragma unroll
        for (int p = 0; p < 4; ++p) {
            float4 wv = *reinterpret_cast<const float4*>(&wr[p * 256 + l * 4]);
            acc += wv.x * qv[p].x + wv.y * qv[p].y + wv.z * qv[p].z + wv.w * qv[p].w;
        }
#pragma unroll
        for (int s = 32; s > 0; s >>= 1) acc += __shfl_xor(acc, s);
        if (l == 0) u[b * D_ + d] = acc;
    }
}

// ---------- scores[b][k] = (h[b,k] . u[b]) / 32 ----------
__global__ __launch_bounds__(256) void k_scores(const u16* __restrict__ h, const float* __restrict__ u,
                                                float* __restrict__ sc) {
    const int b = blockIdx.y;
    const int k = blockIdx.x * 4 + (threadIdx.x >> 6);
    const int l = threadIdx.x & 63;
    const u16* hr = &h[(size_t)(b * S_ + k) * D_];
    const float* ur = &u[b * D_];
    float acc = 0.f;
#pragma unroll
    for (int p = 0; p < 4; ++p) {
        int off = p * 256 + l * 4;
        int2 hv = *reinterpret_cast<const int2*>(&hr[off]);
        float4 uv = *reinterpret_cast<const float4*>(&ur[off]);
        float2 p0 = bf2x2(hv.x), p1 = bf2x2(hv.y);
        acc += p0.x * uv.x + p0.y * uv.y + p1.x * uv.z + p1.y * uv.w;
    }
#pragma unroll
    for (int s = 32; s > 0; s >>= 1) acc += __shfl_xor(acc, s);
    if (l == 0) sc[b * S_ + k] = acc * 0.03125f;
}

// ---------- softmax over k (one block per batch) ----------
__global__ __launch_bounds__(256) void k_softmax(const float* __restrict__ sc, float* __restrict__ wt) {
    const int b = blockIdx.x, tid = threadIdx.x;
    const int w = tid >> 6, l = tid & 63;
    __shared__ float red[4], red2[4];
    float s[8];
    float mx = -1e30f;
#pragma unroll
    for (int j = 0; j < 8; ++j) {
        s[j] = sc[b * S_ + j * 256 + tid];
        mx = fmaxf(mx, s[j]);
    }
#pragma unroll
    for (int t = 32; t > 0; t >>= 1) mx = fmaxf(mx, __shfl_xor(mx, t));
    if (l == 0) red[w] = mx;
    __syncthreads();
    float bm = fmaxf(fmaxf(red[0], red[1]), fmaxf(red[2], red[3]));
    float sum = 0.f;
#pragma unroll
    for (int j = 0; j < 8; ++j) {
        s[j] = expf(s[j] - bm);
        sum += s[j];
    }
#pragma unroll
    for (int t = 32; t > 0; t >>= 1) sum += __shfl_xor(sum, t);
    if (l == 0) red2[w] = sum;
    __syncthreads();
    float inv = 1.f / (red2[0] + red2[1] + red2[2] + red2[3]);
#pragma unroll
    for (int j = 0; j < 8; ++j) wt[b * S_ + j * 256 + tid] = s[j] * inv;
}

// ---------- hbar partial: sum over k-chunk of w[k]*h[b,k,:] ----------
__global__ __launch_bounds__(256) void k_hpart(const u16* __restrict__ h, const float* __restrict__ wt,
                                               float* __restrict__ part) {
    const int kc = blockIdx.x, b = blockIdx.y, tid = threadIdx.x;
    const int d0 = tid * 4;
    float a0 = 0.f, a1 = 0.f, a2 = 0.f, a3 = 0.f;
    for (int k = kc * 128; k < kc * 128 + 128; ++k) {
        float wgt = wt[b * S_ + k];
        int2 hv = *reinterpret_cast<const int2*>(&h[(size_t)(b * S_ + k) * D_ + d0]);
        float2 p0 = bf2x2(hv.x), p1 = bf2x2(hv.y);
        a0 += wgt * p0.x; a1 += wgt * p0.y; a2 += wgt * p1.x; a3 += wgt * p1.y;
    }
    float4 st = {a0, a1, a2, a3};
    *reinterpret_cast<float4*>(&part[(kc * 8 + b) * D_ + d0]) = st;
}

__global__ __launch_bounds__(256) void k_hreduce(const float* __restrict__ part, float* __restrict__ hbar) {
    const int d = blockIdx.x * 256 + threadIdx.x, b = blockIdx.y;
    float s = 0.f;
#pragma unroll
    for (int kc = 0; kc < 16; ++kc) s += part[(kc * 8 + b) * D_ + d];
    hbar[b * D_ + d] = s;
}

// ---------- abar partial: hbar @ Wv over d-chunk ----------
__global__ __launch_bounds__(256) void k_apart(const float* __restrict__ hbar, const float* __restrict__ Wv,
                                               float* __restrict__ part) {
    const int ec = blockIdx.x, dc = blockIdx.y, b = blockIdx.z, tid = threadIdx.x;
    __shared__ float hl[128];
    if (tid < 128) hl[tid] = hbar[b * D_ + dc * 128 + tid];
    __syncthreads();
    const int e = ec * 256 + tid;
    float acc = 0.f;
#pragma unroll 4
    for (int i = 0; i < 128; ++i)
        acc += hl[i] * Wv[(size_t)(dc * 128 + i) * D_ + e];
    part[(dc * 8 + b) * D_ + e] = acc;
}

__global__ __launch_bounds__(256) void k_areduce(const float* __restrict__ part, const float* __restrict__ bv,
                                                 float* __restrict__ abar) {
    const int e = blockIdx.x * 256 + threadIdx.x, b = blockIdx.y;
    float s = bv[e];
#pragma unroll
    for (int dc = 0; dc < 8; ++dc) s += part[(dc * 8 + b) * D_ + e];
    abar[b * D_ + e] = s;
}

// ---------- out partial: abar @ Wo over d-chunk ----------
__global__ __launch_bounds__(256) void k_opart(const float* __restrict__ abar, const float* __restrict__ Wo,
                                               float* __restrict__ part) {
    const int dc = blockIdx.x, b = blockIdx.y, tid = threadIdx.x;
    __shared__ float al[256];
    al[tid] = abar[b * D_ + dc * 256 + tid];
    __syncthreads();
    float acc = 0.f;
#pragma unroll 4
    for (int i = 0; i < 256; ++i)
        acc += al[i] * Wo[(size_t)(dc * 256 + i) * OUT_ + tid];
    part[(dc * 8 + b) * OUT_ + tid] = acc;
}

__global__ __launch_bounds__(256) void k_oreduce(const float* __restrict__ part, const float* __restrict__ bo,
                                                 float* __restrict__ out) {
    const int b = blockIdx.x, tid = threadIdx.x;
    float s = bo[tid];
#pragma unroll
    for (int dc = 0; dc < 4; ++dc) s += part[(dc * 8 + b) * OUT_ + tid];
    out[b * OUT_ + tid] = s;
}

extern "C" void kernel_launch(void* const* d_in, const int* in_sizes, int n_in,
                              void* d_out, int out_size, void* d_ws, size_t ws_size,
                              hipStream_t stream) {
    const float* x  = (const float*)d_in[0];
    const float* Wi = (const float*)d_in[1];
    const float* bi = (const float*)d_in[2];
    const float* Wq = (const float*)d_in[3];
    const float* bq = (const float*)d_in[4];
    const float* Wk = (const float*)d_in[5];
    // d_in[6] = bk : provably unused (softmax shift invariance)
    const float* Wv = (const float*)d_in[7];
    const float* bv = (const float*)d_in[8];
    const float* Wo = (const float*)d_in[9];
    const float* bo = (const float*)d_in[10];
    float* out = (float*)d_out;

    char* ws = (char*)d_ws;
    u16*   WiT   = (u16*)  (ws + OFF_WIT);
    u16*   h     = (u16*)  (ws + OFF_H);
    float* Qpart = (float*)(ws + OFF_QPART);
    float* Q     = (float*)(ws + OFF_Q);
    float* u     = (float*)(ws + OFF_U);
    float* sc    = (float*)(ws + OFF_SC);
    float* wt    = (float*)(ws + OFF_W);
    float* hpart = (float*)(ws + OFF_HPART);
    float* hbar  = (float*)(ws + OFF_HBAR);
    float* apart = (float*)(ws + OFF_APART);
    float* abar  = (float*)(ws + OFF_ABAR);
    float* opart = (float*)(ws + OFF_OPART);

    k_wit    <<<dim3(16, 4),    256, 0, stream>>>(Wi, WiT);
    k_hgemm  <<<dim3(8, 128),   256, 0, stream>>>(x, WiT, bi, h);
    k_qpart  <<<dim3(4, 8, 8),  256, 0, stream>>>(h, Wq, Qpart);
    k_qreduce<<<dim3(4, 8),     256, 0, stream>>>(Qpart, bq, Q);
    k_u      <<<dim3(64, 8),    256, 0, stream>>>(Wk, Q, u);
    k_scores <<<dim3(512, 8),   256, 0, stream>>>(h, u, sc);
    k_softmax<<<dim3(8),        256, 0, stream>>>(sc, wt);
    k_hpart  <<<dim3(16, 8),    256, 0, stream>>>(h, wt, hpart);
    k_hreduce<<<dim3(4, 8),     256, 0, stream>>>(hpart, hbar);
    k_apart  <<<dim3(4, 8, 8),  256, 0, stream>>>(hbar, Wv, apart);
    k_areduce<<<dim3(4, 8),     256, 0, stream>>>(apart, bv, abar);
    k_opart  <<<dim3(4, 8),     256, 0, stream>>>(abar, Wo, opart);
    k_oreduce<<<dim3(8),        256, 0, stream>>>(opart, bo, out);
}